// Round 5
// baseline (143.753 us; speedup 1.0000x reference)
//
#include <hip/hip_runtime.h>
#include <stdint.h>

// Quant3Linear GEMV: y = x @ (scales.T * unpack3(qweight) - zeros.T) + bias
//   x: (1, 8192) f32 | qweight: (768, 28672) i32 | scales,zeros: (28672,1) | bias: (28672,)
// Decomposition: y[o] = scales[o]*dot(x, q[:,o]) - zeros[o]*sum(x) + bias[o]
//
// Stage A (q3_partial): split-K=32 (896 blocks), 4 columns/thread, x staged in
//   LDS (pre-scaled X=8x), rolled loop + depth-1 qweight prefetch.
//   MAGIC-MANTISSA unpack (R5): code c -> float(1 + c/8) via shift+and_or into
//   1.0f's mantissa bits [20:23) -- NO v_cvt (suspected quarter-rate; 235M of
//   them). acc += X*(1+c/8) = 8x + x*c; the 8*S bias folds into finish's
//   zero-correction: out = scales*sum - (8*scales+zeros)*S + bias.
// Stage B (q3_finish): 448 blocks x 64 cols, 4 waves sum 8 partials each,
//   LDS combine; S from partS (128 B) computed free in partial.
// History: SPLIT=64 + full-unroll prefetch regressed (R1/R2, spill);
//   latency ruled out (R1 TLP worse, R3 prefetch neutral); R4 pk+finish -2.4us.

typedef float v2f __attribute__((ext_vector_type(2)));

constexpr int O_FEAT  = 28672;
constexpr int IN_FEAT = 8192;
constexpr int NGROUP  = IN_FEAT / 32;   // 256 groups (3 packed int32 rows each)
constexpr int SPLIT   = 32;             // split-K factor
constexpr int GPB     = NGROUP / SPLIT; // 8 groups per thread
constexpr int O4      = O_FEAT / 4;     // uint4 columns per packed row

// 3-bit field at bit S of w -> float(1 + c/8), no convert:
// shift field to mantissa bits [20:23) of 1.0f. Exact for c in [0,8).
template <int S>
__device__ __forceinline__ float mgf(uint32_t w) {
  uint32_t u = (S < 20) ? ((w << (20 - S)) & 0x00700000u)
                        : ((w >> (S - 20)) & 0x00700000u);
  return __uint_as_float(u | 0x3F800000u);
}

// Unpack one column-group (32 3-bit codes; GPTQ packing: e0..9 @ w0 bits 3j,
// e10 split w0/w1, e11..20 @ w1 bits 3j+1, e21 split w1/w2, e22..31 @ w2 bits
// 3j+2) and accumulate X-dot via v_pk_fma_f32 pairs. xv[k] = {X[2k], X[2k+1]}.
__device__ __forceinline__ void dot_group_mg(uint32_t w0, uint32_t w1, uint32_t w2,
                                             const v2f xv[16], v2f& acc) {
  v2f a0 = acc, a1 = {0.f, 0.f};
  a0 += xv[0] * v2f{mgf<0>(w0),  mgf<3>(w0)};    // e0,e1
  a1 += xv[1] * v2f{mgf<6>(w0),  mgf<9>(w0)};    // e2,e3
  a0 += xv[2] * v2f{mgf<12>(w0), mgf<15>(w0)};   // e4,e5
  a1 += xv[3] * v2f{mgf<18>(w0), mgf<21>(w0)};   // e6,e7
  a0 += xv[4] * v2f{mgf<24>(w0), mgf<27>(w0)};   // e8,e9
  { // e10 = (w0>>30)|((w1&1)<<2) split; e11 = w1 bits [1:4)
    uint32_t e10 = (((w0 >> 10) & 0x00300000u) | 0x3F800000u) | ((w1 << 22) & 0x00400000u);
    a1 += xv[5] * v2f{__uint_as_float(e10), mgf<1>(w1)};
  }
  a0 += xv[6] * v2f{mgf<4>(w1),  mgf<7>(w1)};    // e12,e13
  a1 += xv[7] * v2f{mgf<10>(w1), mgf<13>(w1)};   // e14,e15
  a0 += xv[8] * v2f{mgf<16>(w1), mgf<19>(w1)};   // e16,e17
  a1 += xv[9] * v2f{mgf<22>(w1), mgf<25>(w1)};   // e18,e19
  { // e20 = w1 bits [28:31); e21 = (w1>>31)|((w2&3)<<1) split
    uint32_t e21 = (((w1 >> 11) & 0x00100000u) | 0x3F800000u) | ((w2 << 21) & 0x00600000u);
    a0 += xv[10] * v2f{mgf<28>(w1), __uint_as_float(e21)};
  }
  a1 += xv[11] * v2f{mgf<2>(w2),  mgf<5>(w2)};   // e22,e23
  a0 += xv[12] * v2f{mgf<8>(w2),  mgf<11>(w2)};  // e24,e25
  a1 += xv[13] * v2f{mgf<14>(w2), mgf<17>(w2)};  // e26,e27
  a0 += xv[14] * v2f{mgf<20>(w2), mgf<23>(w2)};  // e28,e29
  a1 += xv[15] * v2f{mgf<26>(w2), mgf<29>(w2)};  // e30,e31
  acc = a0 + a1;
}

__global__ __launch_bounds__(256) void q3_partial(const float* __restrict__ x,
                                                  const uint4* __restrict__ qw4,
                                                  float* __restrict__ part,
                                                  float* __restrict__ partS) {
  const int tcol4 = blockIdx.x * 256 + threadIdx.x;  // index in units of 4 columns
  const int g0    = blockIdx.y * GPB;
  const uint4* qp = qw4 + (size_t)(3 * g0) * O4 + tcol4;

  // Stage this block's x chunk (256 floats = 1 KB) in LDS, pre-scaled by 8
  // (exact pow2) for the magic-mantissa dot: one float per thread.
  __shared__ float xs[GPB * 32];
  const float myx = x[g0 * 32 + threadIdx.x];
  xs[threadIdx.x] = 8.0f * myx;

  // Per-K-range x sum (UNSCALED) -> partS[y]. All 28 bx-blocks of a y-row
  // write the identical value deterministically; redundant write is benign.
  float s = myx;
  #pragma unroll
  for (int off = 32; off > 0; off >>= 1) s += __shfl_down(s, off, 64);
  __shared__ float ls[4];
  if ((threadIdx.x & 63) == 0) ls[threadIdx.x >> 6] = s;
  __syncthreads();
  if (threadIdx.x == 0) partS[blockIdx.y] = (ls[0] + ls[1]) + (ls[2] + ls[3]);

  v2f acc0 = {0.f, 0.f}, acc1 = {0.f, 0.f}, acc2 = {0.f, 0.f}, acc3 = {0.f, 0.f};

  // Rolled loop, depth-1 qweight prefetch (last iter re-loads own rows: L1 hit).
  uint4 na = qp[0], nb = qp[O4], nc = qp[2 * O4];
  for (int g = 0; g < GPB; ++g) {
    const uint4 wa = na, wb = nb, wc = nc;
    qp += (g < GPB - 1) ? 3 * O4 : 0;
    na = qp[0]; nb = qp[O4]; nc = qp[2 * O4];

    v2f xv[16];
    const float4* s4 = reinterpret_cast<const float4*>(&xs[g * 32]);
    #pragma unroll
    for (int u = 0; u < 8; ++u) {
      float4 t = s4[u];
      xv[2 * u]     = v2f{t.x, t.y};
      xv[2 * u + 1] = v2f{t.z, t.w};
    }

    dot_group_mg(wa.x, wb.x, wc.x, xv, acc0);  // 4 independent chains
    dot_group_mg(wa.y, wb.y, wc.y, xv, acc1);
    dot_group_mg(wa.z, wb.z, wc.z, xv, acc2);
    dot_group_mg(wa.w, wb.w, wc.w, xv, acc3);
  }

  float4 r = make_float4(acc0.x + acc0.y, acc1.x + acc1.y,
                         acc2.x + acc2.y, acc3.x + acc3.y);
  reinterpret_cast<float4*>(part)[(size_t)blockIdx.y * O4 + tcol4] = r;
}

__global__ __launch_bounds__(256) void q3_finish(const float* __restrict__ part,
                                                 const float* __restrict__ partS,
                                                 const float* __restrict__ scales,
                                                 const float* __restrict__ zeros,
                                                 const float* __restrict__ bias,
                                                 float* __restrict__ out) {
  const int q  = threadIdx.x >> 6;   // wave id 0..3 -> partial slice
  const int ol = threadIdx.x & 63;   // column within block
  const int o  = blockIdx.x * 64 + ol;

  // S = sum over 32 per-range sums (128 B, broadcast load).
  float S = 0.f;
  #pragma unroll
  for (int i = 0; i < 8; ++i) {
    float4 t = reinterpret_cast<const float4*>(partS)[i];
    S += (t.x + t.y) + (t.z + t.w);
  }

  // Each wave sums 8 partial rows; lanes read 256 B coalesced per row.
  float s0 = 0.f, s1 = 0.f;
  #pragma unroll
  for (int y = 0; y < 8; y += 2) {
    s0 += part[(size_t)(8 * q + y)     * O_FEAT + o];
    s1 += part[(size_t)(8 * q + y + 1) * O_FEAT + o];
  }
  __shared__ float red[4][64];
  red[q][ol] = s0 + s1;
  __syncthreads();
  if (q == 0) {
    float tot = (red[0][ol] + red[1][ol]) + (red[2][ol] + red[3][ol]);
    // sum = 8*S + dot  (magic unpack bias) -> fold 8*scales into zero-corr.
    out[o] = scales[o] * tot - (8.0f * scales[o] + zeros[o]) * S + bias[o];
  }
}

extern "C" void kernel_launch(void* const* d_in, const int* in_sizes, int n_in,
                              void* d_out, int out_size, void* d_ws, size_t ws_size,
                              hipStream_t stream) {
  const float* x      = (const float*)d_in[0];
  const uint4* qw4    = (const uint4*)d_in[1];
  const float* scales = (const float*)d_in[2];
  const float* zeros  = (const float*)d_in[3];
  const float* bias   = (const float*)d_in[4];
  float*       out    = (float*)d_out;
  float*       part   = (float*)d_ws;                       // SPLIT*O_FEAT floats
  float*       partS  = (float*)d_ws + (size_t)SPLIT * O_FEAT;  // + SPLIT floats

  q3_partial<<<dim3(O_FEAT / (256 * 4), SPLIT), dim3(256), 0, stream>>>(x, qw4, part, partS);
  q3_finish<<<dim3(O_FEAT / 64), dim3(256), 0, stream>>>(part, partS, scales, zeros, bias, out);
}

// Round 6
// 143.044 us; speedup vs baseline: 1.0050x; 1.0050x over previous
//
#include <hip/hip_runtime.h>
#include <stdint.h>

// Quant3Linear GEMV: y = x @ (scales.T * unpack3(qweight) - zeros.T) + bias
//   x: (1, 8192) f32 | qweight: (768, 28672) i32 | scales,zeros: (28672,1) | bias: (28672,)
// Decomposition: y[o] = scales[o]*dot(x, q[:,o]) - zeros[o]*sum(x) + bias[o]
//
// Stage A (q3_partial): split-K=32, 64-THREAD SINGLE-WAVE blocks (R6):
//   grid 112x32 = 3584 blocks = exactly 14 waves/CU (was 896 4-wave blocks
//   = 3.5 blocks/CU -> 14% makespan imbalance). Same per-wave loads
//   (3 x dwordx4 rows, depth-1 prefetch), x staged in LDS (1 float4/thread,
//   no barrier needed), pk-paired cvt dot (R4 best).
// Stage B (q3_finish): 448 blocks x 64 cols, 4 waves sum 8 partials each,
//   LDS combine; S from partS (128 B) computed free in partial.
// History: R1/R2 SPLIT=64+unroll regressed (spill); latency ruled out
//   (R1 TLP, R3 prefetch neutral); VALU ruled out (R4 pk, R5 magic ~neutral).

typedef float v2f __attribute__((ext_vector_type(2)));

constexpr int O_FEAT  = 28672;
constexpr int IN_FEAT = 8192;
constexpr int NGROUP  = IN_FEAT / 32;   // 256 groups (3 packed int32 rows each)
constexpr int SPLIT   = 32;             // split-K factor
constexpr int GPB     = NGROUP / SPLIT; // 8 groups per thread
constexpr int O4      = O_FEAT / 4;     // uint4 columns per packed row

// Unpack one column-group (32 3-bit codes in w0,w1,w2; GPTQ packing) and
// accumulate dot with xv[0..15] (f32 pairs). Pair-structured so each pair is
// one v_pk_fma_f32; two v2f chains (a0,a1) cover FMA latency.
__device__ __forceinline__ void dot_group_pk(uint32_t w0, uint32_t w1, uint32_t w2,
                                             const v2f xv[16], v2f& acc) {
  v2f a0 = acc, a1 = {0.f, 0.f};
  #pragma unroll
  for (int t = 0; t < 5; ++t) {   // elements 0..9: w0 bits 3j
    v2f q = { (float)((w0 >> (6 * t)) & 7u), (float)((w0 >> (6 * t + 3)) & 7u) };
    (t & 1 ? a1 : a0) += xv[t] * q;
  }
  { // elements 10 (split w0/w1) and 11 (w1 bit 1)
    v2f q = { (float)((w0 >> 30) | ((w1 & 1u) << 2)), (float)((w1 >> 1) & 7u) };
    a1 += xv[5] * q;
  }
  #pragma unroll
  for (int t = 0; t < 4; ++t) {   // elements 12..19: w1 bits 4+3j
    v2f q = { (float)((w1 >> (4 + 6 * t)) & 7u), (float)((w1 >> (7 + 6 * t)) & 7u) };
    (t & 1 ? a1 : a0) += xv[6 + t] * q;
  }
  { // elements 20 (w1 bit 28) and 21 (split w1/w2)
    v2f q = { (float)((w1 >> 28) & 7u), (float)((w1 >> 31) | ((w2 & 3u) << 1)) };
    a0 += xv[10] * q;
  }
  #pragma unroll
  for (int t = 0; t < 5; ++t) {   // elements 22..31: w2 bits 2+3j
    v2f q = { (float)((w2 >> (2 + 6 * t)) & 7u), (float)((w2 >> (5 + 6 * t)) & 7u) };
    (t & 1 ? a1 : a0) += xv[11 + t] * q;
  }
  acc = a0 + a1;
}

__global__ __launch_bounds__(64) void q3_partial(const float* __restrict__ x,
                                                 const uint4* __restrict__ qw4,
                                                 float* __restrict__ part,
                                                 float* __restrict__ partS) {
  const int tcol4 = blockIdx.x * 64 + threadIdx.x;   // index in units of 4 columns
  const int g0    = blockIdx.y * GPB;
  const uint4* qp = qw4 + (size_t)(3 * g0) * O4 + tcol4;

  // Stage this block's x chunk (256 floats = 1 KB) in LDS: one float4/thread.
  // Single wave per block -> no __syncthreads; compiler orders LDS via lgkmcnt.
  __shared__ float xs[GPB * 32];
  const float4 xt = reinterpret_cast<const float4*>(x + g0 * 32)[threadIdx.x];
  reinterpret_cast<float4*>(xs)[threadIdx.x] = xt;

  // Per-K-range x sum -> partS[y]; only the bx==0 block of each y-row writes.
  if (blockIdx.x == 0) {
    float s = (xt.x + xt.y) + (xt.z + xt.w);
    #pragma unroll
    for (int off = 32; off > 0; off >>= 1) s += __shfl_down(s, off, 64);
    if (threadIdx.x == 0) partS[blockIdx.y] = s;
  }

  v2f acc0 = {0.f, 0.f}, acc1 = {0.f, 0.f}, acc2 = {0.f, 0.f}, acc3 = {0.f, 0.f};

  // Rolled loop, depth-1 qweight prefetch (last iter re-loads own rows: L1 hit).
  uint4 na = qp[0], nb = qp[O4], nc = qp[2 * O4];
  for (int g = 0; g < GPB; ++g) {
    const uint4 wa = na, wb = nb, wc = nc;
    qp += (g < GPB - 1) ? 3 * O4 : 0;
    na = qp[0]; nb = qp[O4]; nc = qp[2 * O4];

    v2f xv[16];
    const float4* s4 = reinterpret_cast<const float4*>(&xs[g * 32]);
    #pragma unroll
    for (int u = 0; u < 8; ++u) {
      float4 t = s4[u];
      xv[2 * u]     = v2f{t.x, t.y};
      xv[2 * u + 1] = v2f{t.z, t.w};
    }

    dot_group_pk(wa.x, wb.x, wc.x, xv, acc0);  // 4 independent chains
    dot_group_pk(wa.y, wb.y, wc.y, xv, acc1);
    dot_group_pk(wa.z, wb.z, wc.z, xv, acc2);
    dot_group_pk(wa.w, wb.w, wc.w, xv, acc3);
  }

  float4 r = make_float4(acc0.x + acc0.y, acc1.x + acc1.y,
                         acc2.x + acc2.y, acc3.x + acc3.y);
  reinterpret_cast<float4*>(part)[(size_t)blockIdx.y * O4 + tcol4] = r;
}

__global__ __launch_bounds__(256) void q3_finish(const float* __restrict__ part,
                                                 const float* __restrict__ partS,
                                                 const float* __restrict__ scales,
                                                 const float* __restrict__ zeros,
                                                 const float* __restrict__ bias,
                                                 float* __restrict__ out) {
  const int q  = threadIdx.x >> 6;   // wave id 0..3 -> partial slice
  const int ol = threadIdx.x & 63;   // column within block
  const int o  = blockIdx.x * 64 + ol;

  // S = sum over 32 per-range sums (128 B, broadcast load).
  float S = 0.f;
  #pragma unroll
  for (int i = 0; i < 8; ++i) {
    float4 t = reinterpret_cast<const float4*>(partS)[i];
    S += (t.x + t.y) + (t.z + t.w);
  }

  // Each wave sums 8 partial rows; lanes read 256 B coalesced per row.
  float s0 = 0.f, s1 = 0.f;
  #pragma unroll
  for (int y = 0; y < 8; y += 2) {
    s0 += part[(size_t)(8 * q + y)     * O_FEAT + o];
    s1 += part[(size_t)(8 * q + y + 1) * O_FEAT + o];
  }
  __shared__ float red[4][64];
  red[q][ol] = s0 + s1;
  __syncthreads();
  if (q == 0) {
    float tot = (red[0][ol] + red[1][ol]) + (red[2][ol] + red[3][ol]);
    out[o] = scales[o] * tot - zeros[o] * S + bias[o];
  }
}

extern "C" void kernel_launch(void* const* d_in, const int* in_sizes, int n_in,
                              void* d_out, int out_size, void* d_ws, size_t ws_size,
                              hipStream_t stream) {
  const float* x      = (const float*)d_in[0];
  const uint4* qw4    = (const uint4*)d_in[1];
  const float* scales = (const float*)d_in[2];
  const float* zeros  = (const float*)d_in[3];
  const float* bias   = (const float*)d_in[4];
  float*       out    = (float*)d_out;
  float*       part   = (float*)d_ws;                       // SPLIT*O_FEAT floats
  float*       partS  = (float*)d_ws + (size_t)SPLIT * O_FEAT;  // + SPLIT floats

  q3_partial<<<dim3(O_FEAT / (64 * 4), SPLIT), dim3(64), 0, stream>>>(x, qw4, part, partS);
  q3_finish<<<dim3(O_FEAT / 64), dim3(256), 0, stream>>>(part, partS, scales, zeros, bias, out);
}